// Round 11
// baseline (101.206 us; speedup 1.0000x reference)
//
#include <hip/hip_runtime.h>

#define BATCH 4
#define NPTS  2048
#define DZDIM 128
#define GD    128
#define M_TOT (GD*GD)
#define TN    64        // k-tile (r10-verified)
#define PZ    72        // Z LDS row pitch (ushorts); 64 data + 8 pad; stride 36 dwords -> 2-way banks (free)
#define ZP    2112      // zt / xs row pitch (elements); 2048 data + 64 pad, 16B-aligned rows
#define WBIN  15        // +-15 bins: covers |x-gx| < 15.5*step (w < 7e-6 outside)

typedef __attribute__((ext_vector_type(8))) __bf16 bf16x8;
typedef __attribute__((ext_vector_type(4))) float floatx4;

__device__ __forceinline__ unsigned int f2bf_bits(float x){
  unsigned int u = __float_as_uint(x);
  u += 0x7FFFu + ((u >> 16) & 1u);
  return u >> 16;
}
__device__ __forceinline__ int point_bin(float px){
  int bin = __float2int_rn((px + 2.0f) * (127.0f / 4.0f));
  return min(GD - 1, max(0, bin));
}

// ---- D1: per-batch hist + scan + atomic-rank scatter — 4 blocks only (xgrid moved to D3) ----
__global__ __launch_bounds__(256) void prep_kernel(
    const float* __restrict__ x, int* __restrict__ binStart,
    float2* __restrict__ xs, int* __restrict__ perm)
{
  const int tid = threadIdx.x;
  __shared__ int h[GD];
  __shared__ int s[GD + 1];
  const int b = blockIdx.x;
  const float2* __restrict__ x2 = (const float2*)x;
  if (tid < GD) h[tid] = 0;
  __syncthreads();
  float2 xv[8]; int bn[8];
#pragma unroll
  for (int u = 0; u < 8; ++u){
    xv[u] = x2[b*NPTS + u*256 + tid];
    bn[u] = point_bin(xv[u].x);
    atomicAdd(&h[bn[u]], 1);
  }
  __syncthreads();
  if (tid == 0){
    int acc = 0;
#pragma unroll
    for (int j = 0; j < GD; ++j){ s[j] = acc; acc += h[j]; }
    s[GD] = acc;
  }
  __syncthreads();
  if (tid <= GD) binStart[b*(GD+1) + tid] = s[tid];
  if (tid < GD) h[tid] = 0;            // reuse as per-bin rank counters
  __syncthreads();
#pragma unroll
  for (int u = 0; u < 8; ++u){
    int j = s[bn[u]] + atomicAdd(&h[bn[u]], 1);   // order in bin arbitrary: sums commute
    xs[(long)b*ZP + j]       = xv[u];
    perm[b*NPTS + j]         = u*256 + tid;
  }
}

// ---- D2: zt[b][dz][j] = bf16(z[b][perm[j]][dz]) — widened to 512 blocks (2/CU, TLP) ----
__global__ __launch_bounds__(256) void ztbuild_kernel(
    const float* __restrict__ z, const int* __restrict__ perm,
    unsigned short* __restrict__ zt)
{
  const int b   = blockIdx.y;
  const int jj  = threadIdx.x & 15;          // 16 j-cols per block
  const int oct = threadIdx.x >> 4;          // 0..15
  const int j = blockIdx.x*16 + jj;
  const int n = perm[b*NPTS + j];
  const float4* __restrict__ z4 = (const float4*)z;
  const long rb = (long)(b*NPTS + n) * 32;
#pragma unroll
  for (int r = 0; r < 2; ++r){
    int c = oct*2 + r;                       // float4 index 0..31 -> dz = 4c..4c+3
    float4 v = z4[rb + c];
    long o = ((long)(b*DZDIM + 4*c) * ZP) + j;
    zt[o        ] = (unsigned short)f2bf_bits(v.x);
    zt[o +   ZP ] = (unsigned short)f2bf_bits(v.y);
    zt[o + 2*ZP ] = (unsigned short)f2bf_bits(v.z);
    zt[o + 3*ZP ] = (unsigned short)f2bf_bits(v.w);
  }
}

// ---- D3: main — r10 skeleton (verified) + fused x_grid row write (block owns row (b,i)) ----
__global__ __launch_bounds__(256, 2) void setconv_mfma_kernel(
    const float2* __restrict__ xs, const int* __restrict__ binStart,
    const unsigned short* __restrict__ zt, const float* __restrict__ lsp,
    const float* __restrict__ gridc, float* __restrict__ out)
{
  __shared__ __align__(16) unsigned short Zlds[2][DZDIM * PZ];  // 2 x 18432 B
  __shared__ __align__(16) float2 XS[2][TN];                    // 2 x 512 B

  const int tid = threadIdx.x, lane = tid & 63, wv = tid >> 6;
  const int bid = blockIdx.x;
  const int g   = bid & 7;                   // XCD pin -> 16-row band (L2 locality)
  const int s   = bid >> 3;
  const int b   = s & 3;
  const int il  = s >> 2;                    // 0..15
  const int i   = g*16 + il;                 // grid row (gx index)

  // fused x_grid broadcast: this block owns output row (b,i); 256 thr x 1 float = 1 KB
  out[(long)b*(M_TOT*2) + i*(GD*2) + tid] = gridc[i*(GD*2) + tid];
  float* __restrict__ outz = out + BATCH*M_TOT*2;

  const float l0 = 1e-5f + log1pf(expf(lsp[0]));
  const float l1 = 1e-5f + log1pf(expf(lsp[1]));
  const float LOG2E = 1.4426950408889634f;
  const float c0 = -0.5f * LOG2E / (l0*l0);
  const float c1 = -0.5f * LOG2E / (l1*l1);
  const float step = 4.0f / 127.0f;
  const float gx   = -2.0f + (float)i * step;

  const int lo  = binStart[b*(GD+1) + max(0, i - WBIN)];
  const int hi  = binStart[b*(GD+1) + min(GD-1, i + WBIN) + 1];
  const int lo8 = lo & ~7;                   // 16B-align k-base (extra pts get true tiny w)
  const int len = hi - lo8;
  const int T   = (len + TN - 1) / TN;

  // Z glds per-lane setup: 18 wave-instrs cover 128 rows x 9 chunks (8 data + 1 pad) of 16B
  int goff[5];
#pragma unroll
  for (int u = 0; u < 5; ++u){
    int gi = wv + 4*u;
    if (gi < 18){
      int pos = gi*64 + lane;                // 16B-chunk index in LDS buffer
      int d = pos / 9, c = pos % 9;          // dz row, chunk-in-row
      if (c > 7) c = 7;                      // pad chunk: duplicate a valid address
      goff[u] = (b*DZDIM + d) * ZP + c*8;
    } else goff[u] = 0;
  }

  const int q  = lane >> 4;
  const int ml = lane & 15;
  const float gy0 = -2.0f + (float)(wv*16 + ml) * step;  // A-frag row (m) of this lane
  const float gy1 = gy0 + 64.0f * step;                  // second A-frag: m + 64

  floatx4 acc[2][8];
#pragma unroll
  for (int hh = 0; hh < 2; ++hh)
#pragma unroll
    for (int tz = 0; tz < 8; ++tz) acc[hh][tz] = (floatx4){0.f, 0.f, 0.f, 0.f};

  auto stageZ = [&](int buf, int t){
    const int k0 = lo8 + t*TN;
#pragma unroll
    for (int u = 0; u < 5; ++u){
      int gi = wv + 4*u;
      if (gi < 18){
        const unsigned short* gp = zt + goff[u] + k0;
        __builtin_amdgcn_global_load_lds(
            (__attribute__((address_space(1))) void*)gp,
            (__attribute__((address_space(3))) void*)&Zlds[buf][gi*512],
            16, 0, 0);
      }
    }
  };
  auto stageXS = [&](int buf, int t){
    if (tid < TN)
      XS[buf][tid] = xs[(long)b*ZP + lo8 + t*TN + tid];  // pad reads in-bounds (ZP)
  };

  if (T > 0){
    stageZ(0, 0);
    stageXS(0, 0);
    __syncthreads();
    for (int t = 0; t < T; ++t){
      const int cur = t & 1, nxt = 1 - cur;
      if (t + 1 < T){ stageZ(nxt, t + 1); stageXS(nxt, t + 1); }
#pragma unroll
      for (int half = 0; half < 2; ++half){
        // in-register weights: one exp2 per (m,k); k-mask via cndmask (NaN-safe)
        float w0[8], w1[8];
#pragma unroll
        for (int r = 0; r < 8; ++r){
          float2 p = XS[cur][half*32 + q*8 + r];         // 16-lane broadcast read
          float dx = gx - p.x;
          float t0 = c0*dx*dx;
          float dy0 = gy0 - p.y, dy1 = gy1 - p.y;
          float a0 = fmaf(c1*dy0, dy0, t0);
          float a1 = fmaf(c1*dy1, dy1, t0);
          bool ok = (t*TN + half*32 + q*8 + r) < len;
          w0[r] = ok ? __builtin_amdgcn_exp2f(a0) : 0.f;
          w1[r] = ok ? __builtin_amdgcn_exp2f(a1) : 0.f;
        }
        union { unsigned int u[4]; bf16x8 v; } A0, A1;
        asm("v_cvt_pk_bf16_f32 %0, %1, %2" : "=v"(A0.u[0]) : "v"(w0[0]), "v"(w0[1]));
        asm("v_cvt_pk_bf16_f32 %0, %1, %2" : "=v"(A0.u[1]) : "v"(w0[2]), "v"(w0[3]));
        asm("v_cvt_pk_bf16_f32 %0, %1, %2" : "=v"(A0.u[2]) : "v"(w0[4]), "v"(w0[5]));
        asm("v_cvt_pk_bf16_f32 %0, %1, %2" : "=v"(A0.u[3]) : "v"(w0[6]), "v"(w0[7]));
        asm("v_cvt_pk_bf16_f32 %0, %1, %2" : "=v"(A1.u[0]) : "v"(w1[0]), "v"(w1[1]));
        asm("v_cvt_pk_bf16_f32 %0, %1, %2" : "=v"(A1.u[1]) : "v"(w1[2]), "v"(w1[3]));
        asm("v_cvt_pk_bf16_f32 %0, %1, %2" : "=v"(A1.u[2]) : "v"(w1[4]), "v"(w1[5]));
        asm("v_cvt_pk_bf16_f32 %0, %1, %2" : "=v"(A1.u[3]) : "v"(w1[6]), "v"(w1[7]));
        bf16x8 af0 = A0.v, af1 = A1.v;
#pragma unroll
        for (int tz = 0; tz < 8; ++tz){
          bf16x8 bf = *(const bf16x8*)&Zlds[cur][(tz*16 + ml)*PZ + half*32 + q*8];
          acc[0][tz] = __builtin_amdgcn_mfma_f32_16x16x32_bf16(af0, bf, acc[0][tz], 0, 0, 0);
          acc[1][tz] = __builtin_amdgcn_mfma_f32_16x16x32_bf16(af1, bf, acc[1][tz], 0, 0, 0);
        }
      }
      __syncthreads();                     // drains vmcnt (Z glds); single barrier per tile
    }
  }

  // epilogue: C/D col(dz)=ml, row(m)=q*4+r; halves at m and m+64
#pragma unroll
  for (int hh = 0; hh < 2; ++hh){
    const long obase = ((long)(b*M_TOT + i*GD + hh*64 + wv*16 + q*4) << 7) + ml;
#pragma unroll
    for (int tz = 0; tz < 8; ++tz)
#pragma unroll
      for (int r = 0; r < 4; ++r)
        outz[obase + ((long)r << 7) + tz*16] = acc[hh][tz][r];
  }
}

extern "C" void kernel_launch(void* const* d_in, const int* in_sizes, int n_in,
                              void* d_out, int out_size, void* d_ws, size_t ws_size,
                              hipStream_t stream)
{
  const float* x    = (const float*)d_in[0];
  const float* z    = (const float*)d_in[1];
  const float* grid = (const float*)d_in[2];
  const float* lsp  = (const float*)d_in[3];
  float* out = (float*)d_out;

  char* ws = (char*)d_ws;
  int*            binStart = (int*)ws;                        // 4*129*4    = 2064 B
  int*            perm     = (int*)(ws + 2064);               // 4*2048*4   = 32768 B
  float2*         xs       = (float2*)(ws + 34832);           // 4*ZP*8     = 67584 B
  unsigned short* zt       = (unsigned short*)(ws + 102416);  // 4*128*ZP*2 = 2162688 B

  hipLaunchKernelGGL(prep_kernel, dim3(BATCH), dim3(256), 0, stream,
                     x, binStart, xs, perm);
  hipLaunchKernelGGL(ztbuild_kernel, dim3(NPTS/16, BATCH), dim3(256), 0, stream,
                     z, perm, zt);
  hipLaunchKernelGGL(setconv_mfma_kernel, dim3(GD*BATCH), dim3(256), 0, stream,
                     xs, binStart, zt, lsp, grid, out);
}